// Round 4
// baseline (70.749 us; speedup 1.0000x reference)
//
#include <hip/hip_runtime.h>
#include <math.h>

// Problem constants (match reference)
static constexpr int Bn  = 256;   // batch
static constexpr int Dd  = 2048;  // feature dim
static constexpr int ATT = 512;   // attribute dim
static constexpr int Cc  = 1024;  // classes
static constexpr int SK1 = 16;    // split-K slices for GEMM1 (K=2048, chunk 128)
static constexpr int SK2 = 8;     // split-K slices for GEMM2 (K=512,  chunk 64)
// TEMP = 4.0 -> 1/TEMP = 0.25, TEMP^2 = 16 ; SCALE = 20.0 ; SCALE/TEMP = 5

// ---------------- reductions (blockDim.x == 256 assumed) ----------------
__device__ __forceinline__ float wave_reduce_sum(float v) {
#pragma unroll
    for (int off = 32; off; off >>= 1) v += __shfl_down(v, off, 64);
    return v;
}
__device__ __forceinline__ float wave_reduce_max(float v) {
#pragma unroll
    for (int off = 32; off; off >>= 1) v = fmaxf(v, __shfl_down(v, off, 64));
    return v;
}
__device__ __forceinline__ float block_reduce_sum(float v) {
    __shared__ float sm_s[4];
    v = wave_reduce_sum(v);
    __syncthreads();
    if ((threadIdx.x & 63) == 0) sm_s[threadIdx.x >> 6] = v;
    __syncthreads();
    return sm_s[0] + sm_s[1] + sm_s[2] + sm_s[3];
}
__device__ __forceinline__ float block_reduce_max(float v) {
    __shared__ float sm_m[4];
    v = wave_reduce_max(v);
    __syncthreads();
    if ((threadIdx.x & 63) == 0) sm_m[threadIdx.x >> 6] = v;
    __syncthreads();
    return fmaxf(fmaxf(sm_m[0], sm_m[1]), fmaxf(sm_m[2], sm_m[3]));
}

// ------- split-K tiled f32 GEMM (NT): part[z][M][N] = A[M,Kc] . B[N,Kc]^T
// 128x64 tile, 8x4 acc per thread (32 FMA per 3 ds_read_b128).
// LDS tiles K-major so fragment reads are ds_read_b128.
template <int BM, int BN, int BK, int KC>
__global__ __launch_bounds__(256) void gemm_nt_splitk(const float* __restrict__ A,
                                                      const float* __restrict__ B,
                                                      float* __restrict__ part,
                                                      int M, int N, int K) {
    __shared__ float As[BK][BM + 4];
    __shared__ float Bs[BK][BN + 4];
    const int tid = threadIdx.x;
    const int tx = tid & 15, ty = tid >> 4;       // 16x16 threads; 8 rows x 4 cols each
    const int row0 = blockIdx.y * BM, col0 = blockIdx.x * BN;
    const int kbase = blockIdx.z * KC;
    float acc[8][4] = {};
    constexpr int FA = BK / 4;                    // float4 per A/B tile row
    for (int k0 = kbase; k0 < kbase + KC; k0 += BK) {
#pragma unroll
        for (int t = tid; t < BM * FA; t += 256) {
            const int r = t / FA, c4 = (t % FA) * 4;
            const float4 v = *(const float4*)(A + (size_t)(row0 + r) * K + k0 + c4);
            As[c4 + 0][r] = v.x; As[c4 + 1][r] = v.y; As[c4 + 2][r] = v.z; As[c4 + 3][r] = v.w;
        }
#pragma unroll
        for (int t = tid; t < BN * FA; t += 256) {
            const int r = t / FA, c4 = (t % FA) * 4;
            const float4 v = *(const float4*)(B + (size_t)(col0 + r) * K + k0 + c4);
            Bs[c4 + 0][r] = v.x; Bs[c4 + 1][r] = v.y; Bs[c4 + 2][r] = v.z; Bs[c4 + 3][r] = v.w;
        }
        __syncthreads();
#pragma unroll
        for (int k = 0; k < BK; ++k) {
            const float4 a0 = *(const float4*)&As[k][ty * 8];
            const float4 a1 = *(const float4*)&As[k][ty * 8 + 4];
            const float4 b4 = *(const float4*)&Bs[k][tx * 4];
            const float a[8] = {a0.x, a0.y, a0.z, a0.w, a1.x, a1.y, a1.z, a1.w};
            const float b[4] = {b4.x, b4.y, b4.z, b4.w};
#pragma unroll
            for (int u = 0; u < 8; ++u)
#pragma unroll
                for (int w = 0; w < 4; ++w) acc[u][w] = fmaf(a[u], b[w], acc[u][w]);
        }
        __syncthreads();
    }
    float* dst = part + (size_t)blockIdx.z * M * N;
#pragma unroll
    for (int u = 0; u < 8; ++u) {
        const int r = row0 + ty * 8 + u;
        float4 o = make_float4(acc[u][0], acc[u][1], acc[u][2], acc[u][3]);
        *(float4*)(dst + (size_t)r * N + col0 + tx * 4) = o;
    }
}

// ------- fused norm kernel --------
// blocks [0,256):    ya[m] = l2norm(bias + sum_s part1[s][m][:])   (512 cols)
// blocks [256,1280): sa[r] = l2norm(seen[r])                       (512 cols)
__global__ __launch_bounds__(256) void norm_fused(const float* __restrict__ part,
                                                  const float* __restrict__ bias,
                                                  const float* __restrict__ seen,
                                                  float* __restrict__ ya,
                                                  float* __restrict__ sa) {
    const int tid = threadIdx.x;
    if ((int)blockIdx.x < Bn) {
        const int m = blockIdx.x;
        const int c = tid * 2;
        float2 s = *(const float2*)(bias + c);
#pragma unroll
        for (int z = 0; z < SK1; ++z) {
            const float2 p = *(const float2*)(part + (size_t)z * Bn * ATT + (size_t)m * ATT + c);
            s.x += p.x; s.y += p.y;
        }
        float ss = block_reduce_sum(fmaf(s.x, s.x, s.y * s.y));
        const float sc = 1.0f / fmaxf(sqrtf(ss), 1e-12f);
        *(float2*)(ya + (size_t)m * ATT + c) = make_float2(s.x * sc, s.y * sc);
    } else {
        const int r = blockIdx.x - Bn;
        const int c = tid * 2;
        const float2 v = *(const float2*)(seen + (size_t)r * ATT + c);
        float ss = block_reduce_sum(fmaf(v.x, v.x, v.y * v.y));
        const float sc = 1.0f / fmaxf(sqrtf(ss), 1e-12f);
        *(float2*)(sa + (size_t)r * ATT + c) = make_float2(v.x * sc, v.y * sc);
    }
}

// ------- fused: logits = 5 * sum_s part2 ; softmax -> P, negH (block per row, C=1024)
__global__ __launch_bounds__(256) void reduce_softmax(const float* __restrict__ part,
                                                      float* __restrict__ P,
                                                      float* __restrict__ negH) {
    const int i = blockIdx.x;
    const int c = threadIdx.x * 4;
    float4 a = make_float4(0.f, 0.f, 0.f, 0.f);
#pragma unroll
    for (int z = 0; z < SK2; ++z) {
        const float4 p = *(const float4*)(part + (size_t)z * Bn * Cc + (size_t)i * Cc + c);
        a.x += p.x; a.y += p.y; a.z += p.z; a.w += p.w;
    }
    float lv[4] = {a.x * 5.0f, a.y * 5.0f, a.z * 5.0f, a.w * 5.0f};  // (SCALE/TEMP)
    float lm = fmaxf(fmaxf(lv[0], lv[1]), fmaxf(lv[2], lv[3]));
    lm = block_reduce_max(lm);
    float se = 0.f;
#pragma unroll
    for (int k = 0; k < 4; ++k) se += __expf(lv[k] - lm);
    se = block_reduce_sum(se);
    const float logZ = __logf(se);
    float nh = 0.f;
    float4 pv;
#pragma unroll
    for (int k = 0; k < 4; ++k) {
        const float lp = lv[k] - lm - logZ;
        const float p = __expf(lp);
        (&pv.x)[k] = p;
        nh = fmaf(p, lp, nh);
    }
    *(float4*)(P + (size_t)i * Cc + c) = pv;
    nh = block_reduce_sum(nh);
    if (threadIdx.x == 0) negH[i] = nh;
}

// ---------------- JS over masked pairs, no pair list, no atomics ----------------
// Block i: stage labels in LDS, hold P_i in regs, loop j>i with lbl[j]==lbl[i].
// JS_ij = 0.5*(negH_i + negH_j - sum_c (P_i+P_j)*log((P_i+P_j)/2))
__global__ __launch_bounds__(256) void pair_js_direct(const float* __restrict__ P,
                                                      const float* __restrict__ negH,
                                                      const int* __restrict__ labels,
                                                      float* __restrict__ pairSum,
                                                      float* __restrict__ pairCnt) {
    const int i = blockIdx.x;
    __shared__ int lbl[Bn];
    for (int t = threadIdx.x; t < Bn; t += 256) lbl[t] = labels[t];
    __syncthreads();
    const int li = lbl[i];

    const float* Pi = P + (size_t)i * Cc;
    const float4 pi = *(const float4*)(Pi + threadIdx.x * 4);
    const float nhi = negH[i];

    float sum = 0.f, cnt = 0.f;
    for (int j = i + 1; j < Bn; ++j) {
        if (lbl[j] != li) continue;            // uniform across block
        const float4 pj = *(const float4*)(P + (size_t)j * Cc + threadIdx.x * 4);
        float s = 0.f;
        {
            float t;
            t = pi.x + pj.x; s = fmaf(t, __logf(0.5f * t), s);
            t = pi.y + pj.y; s = fmaf(t, __logf(0.5f * t), s);
            t = pi.z + pj.z; s = fmaf(t, __logf(0.5f * t), s);
            t = pi.w + pj.w; s = fmaf(t, __logf(0.5f * t), s);
        }
        s = block_reduce_sum(s);
        if (threadIdx.x == 0) {
            sum += 0.5f * (nhi + negH[j] - s);
            cnt += 1.0f;
        }
    }
    if (threadIdx.x == 0) { pairSum[i] = sum; pairCnt[i] = cnt; }
}

// ---------------- finalize: reduce per-row partials ----------------
__global__ __launch_bounds__(256) void finalize(const float* __restrict__ pairSum,
                                                const float* __restrict__ pairCnt,
                                                float* __restrict__ out) {
    const float s = block_reduce_sum(pairSum[threadIdx.x]);
    __syncthreads();
    const float c = block_reduce_sum(pairCnt[threadIdx.x]);
    if (threadIdx.x == 0)
        out[0] = (c == 0.0f) ? 0.0f : (s / c) * 16.0f;   // * TEMP^2
}

extern "C" void kernel_launch(void* const* d_in, const int* in_sizes, int n_in,
                              void* d_out, int out_size, void* d_ws, size_t ws_size,
                              hipStream_t stream) {
    const float* x      = (const float*)d_in[0];  // [256, 2048]
    const int*   labels = (const int*)d_in[1];    // [256]
    const float* W      = (const float*)d_in[2];  // [512, 2048]
    const float* bias   = (const float*)d_in[3];  // [512]
    const float* seen   = (const float*)d_in[4];  // [1024, 512]
    float* out = (float*)d_out;

    char* ws = (char*)d_ws;
    // 8 MB split-K partial region, reused by GEMM1 (16x256x512) then GEMM2 (8x256x1024)
    float* part    = (float*)(ws);                         // 8 MB
    float* sa      = (float*)(ws + (8u << 20));            // 1024*512 f32 = 2 MB
    float* ya      = (float*)(ws + (10u << 20));           // 256*512  f32 = 512 KB
    float* P       = (float*)(ws + (10u << 20) + (512u << 10)); // 256*1024 f32 = 1 MB
    float* negH    = (float*)(ws + (11u << 20) + (512u << 10)); // 256 f32
    float* pairSum = negH + Bn;                            // 256 f32
    float* pairCnt = pairSum + Bn;                         // 256 f32

    // GEMM1: y = x . W^T   (M=256, N=512, K=2048), 128x64 tiles, split-K 16
    gemm_nt_splitk<128, 64, 32, 128><<<dim3(ATT / 64, Bn / 128, SK1), 256, 0, stream>>>(
        x, W, part, Bn, ATT, Dd);
    // fused: reduce+bias+l2norm(ya)  ||  l2norm(seen)->sa
    norm_fused<<<Bn + Cc, 256, 0, stream>>>(part, bias, seen, ya, sa);
    // GEMM2: logits_raw = ya . sa^T (M=256, N=1024, K=512), split-K 8
    gemm_nt_splitk<128, 64, 32, 64><<<dim3(Cc / 64, Bn / 128, SK2), 256, 0, stream>>>(
        ya, sa, part, Bn, Cc, ATT);
    reduce_softmax<<<Bn, 256, 0, stream>>>(part, P, negH);
    pair_js_direct<<<Bn, 256, 0, stream>>>(P, negH, labels, pairSum, pairCnt);
    finalize<<<1, 256, 0, stream>>>(pairSum, pairCnt, out);
}

// Round 5
// 64.775 us; speedup vs baseline: 1.0922x; 1.0922x over previous
//
#include <hip/hip_runtime.h>
#include <math.h>

// Problem constants (match reference)
static constexpr int Bn  = 256;   // batch
static constexpr int Dd  = 2048;  // feature dim
static constexpr int ATT = 512;   // attribute dim
static constexpr int Cc  = 1024;  // classes
static constexpr int SK1 = 16;    // split-K slices for GEMM1 (K=2048, chunk 128)
static constexpr int SK2 = 8;     // split-K slices for GEMM2 (K=512,  chunk 64)
// TEMP = 4.0 -> 1/TEMP = 0.25, TEMP^2 = 16 ; SCALE = 20.0 ; SCALE/TEMP = 5

// ---------------- reductions (blockDim.x == 256 assumed) ----------------
__device__ __forceinline__ float wave_reduce_sum(float v) {
#pragma unroll
    for (int off = 32; off; off >>= 1) v += __shfl_down(v, off, 64);
    return v;
}
__device__ __forceinline__ float wave_reduce_max(float v) {
#pragma unroll
    for (int off = 32; off; off >>= 1) v = fmaxf(v, __shfl_down(v, off, 64));
    return v;
}
__device__ __forceinline__ float block_reduce_sum(float v) {
    __shared__ float sm_s[4];
    v = wave_reduce_sum(v);
    __syncthreads();
    if ((threadIdx.x & 63) == 0) sm_s[threadIdx.x >> 6] = v;
    __syncthreads();
    return sm_s[0] + sm_s[1] + sm_s[2] + sm_s[3];
}
__device__ __forceinline__ float block_reduce_max(float v) {
    __shared__ float sm_m[4];
    v = wave_reduce_max(v);
    __syncthreads();
    if ((threadIdx.x & 63) == 0) sm_m[threadIdx.x >> 6] = v;
    __syncthreads();
    return fmaxf(fmaxf(sm_m[0], sm_m[1]), fmaxf(sm_m[2], sm_m[3]));
}

// ------- split-K tiled f32 GEMM (NT): part[z][M][N] = A[M,Kc] . B[N,Kc]^T
// 128x64 tile, 8x4 acc per thread. Register-prefetch double buffering:
// next tile's global loads are issued before the FMA block, waited at LDS-write.
template <int BM, int BN, int BK, int KC>
__global__ __launch_bounds__(256) void gemm_nt_splitk(const float* __restrict__ A,
                                                      const float* __restrict__ B,
                                                      float* __restrict__ part,
                                                      int M, int N, int K) {
    __shared__ float As[BK][BM + 4];
    __shared__ float Bs[BK][BN + 4];
    constexpr int FA = BK / 4;               // float4 per row of K-chunk
    constexpr int NA = BM * FA / 256;        // per-thread A float4 count
    constexpr int NB = BN * FA / 256;        // per-thread B float4 count
    const int tid = threadIdx.x;
    const int tx = tid & 15, ty = tid >> 4;  // 16x16 threads; 8 rows x 4 cols each
    const int row0 = blockIdx.y * BM, col0 = blockIdx.x * BN;
    const int kbase = blockIdx.z * KC;

    float4 pa[NA], pb[NB];
    // stage first tile into registers
#pragma unroll
    for (int u = 0; u < NA; ++u) {
        const int t = tid + u * 256, r = t / FA, c4 = (t % FA) * 4;
        pa[u] = *(const float4*)(A + (size_t)(row0 + r) * K + kbase + c4);
    }
#pragma unroll
    for (int u = 0; u < NB; ++u) {
        const int t = tid + u * 256, r = t / FA, c4 = (t % FA) * 4;
        pb[u] = *(const float4*)(B + (size_t)(col0 + r) * K + kbase + c4);
    }

    float acc[8][4] = {};
    for (int k0 = kbase; k0 < kbase + KC; k0 += BK) {
        // write staged registers to LDS (transposed, K-major)
#pragma unroll
        for (int u = 0; u < NA; ++u) {
            const int t = tid + u * 256, r = t / FA, c4 = (t % FA) * 4;
            As[c4 + 0][r] = pa[u].x; As[c4 + 1][r] = pa[u].y;
            As[c4 + 2][r] = pa[u].z; As[c4 + 3][r] = pa[u].w;
        }
#pragma unroll
        for (int u = 0; u < NB; ++u) {
            const int t = tid + u * 256, r = t / FA, c4 = (t % FA) * 4;
            Bs[c4 + 0][r] = pb[u].x; Bs[c4 + 1][r] = pb[u].y;
            Bs[c4 + 2][r] = pb[u].z; Bs[c4 + 3][r] = pb[u].w;
        }
        __syncthreads();
        // issue next tile's global loads (in flight during FMA block)
        if (k0 + BK < kbase + KC) {
            const int kn = k0 + BK;
#pragma unroll
            for (int u = 0; u < NA; ++u) {
                const int t = tid + u * 256, r = t / FA, c4 = (t % FA) * 4;
                pa[u] = *(const float4*)(A + (size_t)(row0 + r) * K + kn + c4);
            }
#pragma unroll
            for (int u = 0; u < NB; ++u) {
                const int t = tid + u * 256, r = t / FA, c4 = (t % FA) * 4;
                pb[u] = *(const float4*)(B + (size_t)(col0 + r) * K + kn + c4);
            }
        }
        // FMA block
#pragma unroll
        for (int k = 0; k < BK; ++k) {
            const float4 a0 = *(const float4*)&As[k][ty * 8];
            const float4 a1 = *(const float4*)&As[k][ty * 8 + 4];
            const float4 b4 = *(const float4*)&Bs[k][tx * 4];
            const float a[8] = {a0.x, a0.y, a0.z, a0.w, a1.x, a1.y, a1.z, a1.w};
            const float b[4] = {b4.x, b4.y, b4.z, b4.w};
#pragma unroll
            for (int u = 0; u < 8; ++u)
#pragma unroll
                for (int w = 0; w < 4; ++w) acc[u][w] = fmaf(a[u], b[w], acc[u][w]);
        }
        __syncthreads();
    }
    float* dst = part + (size_t)blockIdx.z * M * N;
#pragma unroll
    for (int u = 0; u < 8; ++u) {
        const int r = row0 + ty * 8 + u;
        float4 o = make_float4(acc[u][0], acc[u][1], acc[u][2], acc[u][3]);
        *(float4*)(dst + (size_t)r * N + col0 + tx * 4) = o;
    }
}

// ------- fused norm kernel --------
// blocks [0,256):    ya[m] = l2norm(bias + sum_s part1[s][m][:])   (512 cols)
// blocks [256,1280): sa[r] = l2norm(seen[r])                       (512 cols)
__global__ __launch_bounds__(256) void norm_fused(const float* __restrict__ part,
                                                  const float* __restrict__ bias,
                                                  const float* __restrict__ seen,
                                                  float* __restrict__ ya,
                                                  float* __restrict__ sa) {
    const int tid = threadIdx.x;
    if ((int)blockIdx.x < Bn) {
        const int m = blockIdx.x;
        const int c = tid * 2;
        float2 s = *(const float2*)(bias + c);
#pragma unroll
        for (int z = 0; z < SK1; ++z) {
            const float2 p = *(const float2*)(part + (size_t)z * Bn * ATT + (size_t)m * ATT + c);
            s.x += p.x; s.y += p.y;
        }
        float ss = block_reduce_sum(fmaf(s.x, s.x, s.y * s.y));
        const float sc = 1.0f / fmaxf(sqrtf(ss), 1e-12f);
        *(float2*)(ya + (size_t)m * ATT + c) = make_float2(s.x * sc, s.y * sc);
    } else {
        const int r = blockIdx.x - Bn;
        const int c = tid * 2;
        const float2 v = *(const float2*)(seen + (size_t)r * ATT + c);
        float ss = block_reduce_sum(fmaf(v.x, v.x, v.y * v.y));
        const float sc = 1.0f / fmaxf(sqrtf(ss), 1e-12f);
        *(float2*)(sa + (size_t)r * ATT + c) = make_float2(v.x * sc, v.y * sc);
    }
}

// ------- fused: logits = 5 * sum_s part2 ; softmax -> P, negH (block per row, C=1024)
__global__ __launch_bounds__(256) void reduce_softmax(const float* __restrict__ part,
                                                      float* __restrict__ P,
                                                      float* __restrict__ negH) {
    const int i = blockIdx.x;
    const int c = threadIdx.x * 4;
    float4 a = make_float4(0.f, 0.f, 0.f, 0.f);
#pragma unroll
    for (int z = 0; z < SK2; ++z) {
        const float4 p = *(const float4*)(part + (size_t)z * Bn * Cc + (size_t)i * Cc + c);
        a.x += p.x; a.y += p.y; a.z += p.z; a.w += p.w;
    }
    float lv[4] = {a.x * 5.0f, a.y * 5.0f, a.z * 5.0f, a.w * 5.0f};  // (SCALE/TEMP)
    float lm = fmaxf(fmaxf(lv[0], lv[1]), fmaxf(lv[2], lv[3]));
    lm = block_reduce_max(lm);
    float se = 0.f;
#pragma unroll
    for (int k = 0; k < 4; ++k) se += __expf(lv[k] - lm);
    se = block_reduce_sum(se);
    const float logZ = __logf(se);
    float nh = 0.f;
    float4 pv;
#pragma unroll
    for (int k = 0; k < 4; ++k) {
        const float lp = lv[k] - lm - logZ;
        const float p = __expf(lp);
        (&pv.x)[k] = p;
        nh = fmaf(p, lp, nh);
    }
    *(float4*)(P + (size_t)i * Cc + c) = pv;
    nh = block_reduce_sum(nh);
    if (threadIdx.x == 0) negH[i] = nh;
}

// ---------------- JS over masked pairs, class-dim split x2 ----------------
// Block (i, half): row i, columns [half*512, half*512+512).
// half 0 carries the negH terms and the pair count.
// JS_ij = 0.5*(negH_i + negH_j - sum_c (P_i+P_j)*log((P_i+P_j)/2))
__global__ __launch_bounds__(256) void pair_js_direct(const float* __restrict__ P,
                                                      const float* __restrict__ negH,
                                                      const int* __restrict__ labels,
                                                      float* __restrict__ pairSum,
                                                      float* __restrict__ pairCnt) {
    const int i = blockIdx.x >> 1, half = blockIdx.x & 1;
    __shared__ int lbl[Bn];
    for (int t = threadIdx.x; t < Bn; t += 256) lbl[t] = labels[t];
    __syncthreads();
    const int li = lbl[i];
    const int cbase = half * (Cc / 2) + threadIdx.x * 2;

    const float2 pi = *(const float2*)(P + (size_t)i * Cc + cbase);
    const float nhi = negH[i];

    float sum = 0.f, cnt = 0.f;
    for (int j = i + 1; j < Bn; ++j) {
        if (lbl[j] != li) continue;            // uniform across block
        const float2 pj = *(const float2*)(P + (size_t)j * Cc + cbase);
        float s = 0.f, t;
        t = pi.x + pj.x; s = fmaf(t, __logf(0.5f * t), s);
        t = pi.y + pj.y; s = fmaf(t, __logf(0.5f * t), s);
        s = block_reduce_sum(s);
        if (threadIdx.x == 0) {
            sum += (half == 0) ? 0.5f * (nhi + negH[j] - s) : -0.5f * s;
            cnt += 1.0f;
        }
    }
    if (threadIdx.x == 0) {
        pairSum[blockIdx.x] = sum;
        if (half == 0) pairCnt[i] = cnt;
    }
}

// ---------------- finalize: reduce per-block partials ----------------
__global__ __launch_bounds__(256) void finalize(const float* __restrict__ pairSum,
                                                const float* __restrict__ pairCnt,
                                                float* __restrict__ out) {
    float s = pairSum[threadIdx.x] + pairSum[threadIdx.x + 256];
    s = block_reduce_sum(s);
    __syncthreads();
    const float c = block_reduce_sum(pairCnt[threadIdx.x]);
    if (threadIdx.x == 0)
        out[0] = (c == 0.0f) ? 0.0f : (s / c) * 16.0f;   // * TEMP^2
}

extern "C" void kernel_launch(void* const* d_in, const int* in_sizes, int n_in,
                              void* d_out, int out_size, void* d_ws, size_t ws_size,
                              hipStream_t stream) {
    const float* x      = (const float*)d_in[0];  // [256, 2048]
    const int*   labels = (const int*)d_in[1];    // [256]
    const float* W      = (const float*)d_in[2];  // [512, 2048]
    const float* bias   = (const float*)d_in[3];  // [512]
    const float* seen   = (const float*)d_in[4];  // [1024, 512]
    float* out = (float*)d_out;

    char* ws = (char*)d_ws;
    // 8 MB split-K partial region, reused by GEMM1 (16x256x512) then GEMM2 (8x256x1024)
    float* part    = (float*)(ws);                         // 8 MB
    float* sa      = (float*)(ws + (8u << 20));            // 1024*512 f32 = 2 MB
    float* ya      = (float*)(ws + (10u << 20));           // 256*512  f32 = 512 KB
    float* P       = (float*)(ws + (10u << 20) + (512u << 10)); // 256*1024 f32 = 1 MB
    float* negH    = (float*)(ws + (11u << 20) + (512u << 10)); // 256 f32
    float* pairSum = negH + Bn;                            // 512 f32
    float* pairCnt = pairSum + 2 * Bn;                     // 256 f32

    // GEMM1: y = x . W^T   (M=256, N=512, K=2048), 128x64 tiles, split-K 16
    gemm_nt_splitk<128, 64, 32, 128><<<dim3(ATT / 64, Bn / 128, SK1), 256, 0, stream>>>(
        x, W, part, Bn, ATT, Dd);
    // fused: reduce+bias+l2norm(ya)  ||  l2norm(seen)->sa
    norm_fused<<<Bn + Cc, 256, 0, stream>>>(part, bias, seen, ya, sa);
    // GEMM2: logits_raw = ya . sa^T (M=256, N=1024, K=512), split-K 8
    gemm_nt_splitk<128, 64, 32, 64><<<dim3(Cc / 64, Bn / 128, SK2), 256, 0, stream>>>(
        ya, sa, part, Bn, Cc, ATT);
    reduce_softmax<<<Bn, 256, 0, stream>>>(part, P, negH);
    pair_js_direct<<<2 * Bn, 256, 0, stream>>>(P, negH, labels, pairSum, pairCnt);
    finalize<<<1, 256, 0, stream>>>(pairSum, pairCnt, out);
}